// Round 1
// baseline (3000.255 us; speedup 1.0000x reference)
//
#include <hip/hip_runtime.h>
#include <hip/hip_bf16.h>

typedef __attribute__((ext_vector_type(8))) short  short8;   // 8 bf16 (4 VGPRs) MFMA frag
typedef __attribute__((ext_vector_type(4))) float  f32x4;    // MFMA accum frag
typedef __attribute__((ext_vector_type(4))) unsigned int u32x4;

#define T_TOTAL 512
#define BATCH   64
#define EMB     512
#define RNN     1024
#define G3      3072      // 3*RNN
#define WROWS   48        // 3 gates x 16 units per WG
#define WPAD    1032      // LDS row stride (shorts): 16B-aligned, 2-way bank alias (free)
#define RPAD    18        // red[] batch stride (floats): max 2-way (free)
#define NWG     256
// LDS: weights 48*1032*2 = 99072 + red double-buffer 2*4*48*18*4 = 27648
#define SMEM_BYTES (WROWS * WPAD * 2 + 2 * 4 * WROWS * RPAD * 4)   // 126720

// ---- bf16 helpers ----
__device__ __forceinline__ unsigned short f2bf(float f) {
    union { float f; unsigned int u; } v; v.f = f;
    unsigned int r = v.u + 0x7fffu + ((v.u >> 16) & 1u);   // round-nearest-even
    return (unsigned short)(r >> 16);
}
__device__ __forceinline__ float bf2f(unsigned short h) {
    union { unsigned int u; float f; } v; v.u = ((unsigned int)h) << 16;
    return v.f;
}
__device__ __forceinline__ float sigmoidf_(float x) { return 1.f / (1.f + __expf(-x)); }
__device__ __forceinline__ float tanhf_(float x) {
    float ax = fabsf(x);
    float e2 = __expf(-2.f * ax);
    float t  = (1.f - e2) / (1.f + e2);
    return x < 0.f ? -t : t;
}

// Per-replay epoch bump: tags = epoch*1024 + step. Guarantees the terminal
// tags of the previous graph replay (epoch' = epoch-1: max tag epoch'*1024+512)
// can never alias any tag of the current replay (offset 1024 > 512).
__global__ void epoch_kernel(unsigned int* ep) { if (threadIdx.x == 0) ++*ep; }

// ============================================================================
// K1: gi = emb_table[x] @ w_ih^T + b_ih, 128x128 tile (m93 pattern). Unchanged.
// ============================================================================
__global__ __launch_bounds__(256) void gi_kernel(
    const int* __restrict__ x, const float* __restrict__ emb,
    const float* __restrict__ w_ih, const float* __restrict__ b_ih,
    unsigned short* __restrict__ gi, int t0)
{
    __shared__ __align__(16) unsigned short Asm[128 * 40];
    __shared__ __align__(16) unsigned short Bsm[128 * 40];

    const int tid = threadIdx.x;
    const int m0 = blockIdx.x * 128;        // local row (t_local*64 + b)
    const int n0 = blockIdx.y * 128;

    const int r    = tid >> 1;              // 0..127
    const int half = tid & 1;               // 16-float half of the 32-col chunk
    const int xi = x[t0 * BATCH + m0 + r];  // gather index (global row)
    const float* arow = emb  + (size_t)xi * EMB + half * 16;
    const float* brow = w_ih + (size_t)(n0 + r) * EMB + half * 16;
    unsigned short* adst = &Asm[r * 40 + half * 16];
    unsigned short* bdst = &Bsm[r * 40 + half * 16];

    const int lane = tid & 63, wv = tid >> 6;
    const int m_off = (wv & 1) * 64, n_off = (wv >> 1) * 64;
    const int lr = lane & 15, lq = lane >> 4;

    f32x4 acc[4][4];
    #pragma unroll
    for (int i = 0; i < 4; ++i)
        #pragma unroll
        for (int j = 0; j < 4; ++j) acc[i][j] = (f32x4){0.f, 0.f, 0.f, 0.f};

    for (int k0 = 0; k0 < EMB; k0 += 32) {
        const float4 a0 = *(const float4*)(arow + k0);
        const float4 a1 = *(const float4*)(arow + k0 + 4);
        const float4 a2 = *(const float4*)(arow + k0 + 8);
        const float4 a3 = *(const float4*)(arow + k0 + 12);
        const float4 b0 = *(const float4*)(brow + k0);
        const float4 b1 = *(const float4*)(brow + k0 + 4);
        const float4 b2 = *(const float4*)(brow + k0 + 8);
        const float4 b3 = *(const float4*)(brow + k0 + 12);
        __syncthreads();  // previous iter's frag reads done
        short8 av0, av1, bv0, bv1;
        av0[0]=f2bf(a0.x); av0[1]=f2bf(a0.y); av0[2]=f2bf(a0.z); av0[3]=f2bf(a0.w);
        av0[4]=f2bf(a1.x); av0[5]=f2bf(a1.y); av0[6]=f2bf(a1.z); av0[7]=f2bf(a1.w);
        av1[0]=f2bf(a2.x); av1[1]=f2bf(a2.y); av1[2]=f2bf(a2.z); av1[3]=f2bf(a2.w);
        av1[4]=f2bf(a3.x); av1[5]=f2bf(a3.y); av1[6]=f2bf(a3.z); av1[7]=f2bf(a3.w);
        bv0[0]=f2bf(b0.x); bv0[1]=f2bf(b0.y); bv0[2]=f2bf(b0.z); bv0[3]=f2bf(b0.w);
        bv0[4]=f2bf(b1.x); bv0[5]=f2bf(b1.y); bv0[6]=f2bf(b1.z); bv0[7]=f2bf(b1.w);
        bv1[0]=f2bf(b2.x); bv1[1]=f2bf(b2.y); bv1[2]=f2bf(b2.z); bv1[3]=f2bf(b2.w);
        bv1[4]=f2bf(b3.x); bv1[5]=f2bf(b3.y); bv1[6]=f2bf(b3.z); bv1[7]=f2bf(b3.w);
        *(short8*)(adst)     = av0;
        *(short8*)(adst + 8) = av1;
        *(short8*)(bdst)     = bv0;
        *(short8*)(bdst + 8) = bv1;
        __syncthreads();

        short8 fa[4], fb[4];
        #pragma unroll
        for (int i = 0; i < 4; ++i) {
            fa[i] = *(const short8*)&Asm[(m_off + i * 16 + lr) * 40 + lq * 8];
            fb[i] = *(const short8*)&Bsm[(n_off + i * 16 + lr) * 40 + lq * 8];
        }
        #pragma unroll
        for (int mi = 0; mi < 4; ++mi)
            #pragma unroll
            for (int ni = 0; ni < 4; ++ni)
                acc[mi][ni] = __builtin_amdgcn_mfma_f32_16x16x32_bf16(
                    fa[mi], fb[ni], acc[mi][ni], 0, 0, 0);
    }

    float bia[4];
    #pragma unroll
    for (int ni = 0; ni < 4; ++ni) bia[ni] = b_ih[n0 + n_off + ni * 16 + lr];
    #pragma unroll
    for (int mi = 0; mi < 4; ++mi)
        #pragma unroll
        for (int ni = 0; ni < 4; ++ni) {
            const int n = n0 + n_off + ni * 16 + lr;
            #pragma unroll
            for (int q = 0; q < 4; ++q) {
                const int m = m0 + m_off + mi * 16 + lq * 4 + q;  // C: row=lq*4+q
                gi[(size_t)m * G3 + n] = f2bf(acc[mi][ni][q] + bia[ni]);
            }
        }
}

// ============================================================================
// K2: recurrence, barrier-free tagged-h exchange.
// h element = u32: (tag16 << 16) | bf16(h), tag = epoch*1024 + step.
// Producers: 256 fire-and-forget dword stores per WG per step (no drain, no
// atomic RMW, no flag). Consumers: each wave polls ITS OWN 256 B fragment;
// per-dword tag equality is the freshness proof (no cross-address ordering
// needed). Cheap 8-dword prefilter spin bounds miss-iteration bandwidth;
// full dwordx4 sc0 sc1 load + full verify gates correctness.
// red[] double-buffered by step parity -> one __syncthreads per step.
// ============================================================================
__global__ __launch_bounds__(256, 1) void rec_kernel(
    const unsigned short* __restrict__ gi,
    const float* __restrict__ w_hh, const float* __restrict__ b_hh,
    unsigned int* __restrict__ hb0, unsigned int* __restrict__ hb1,
    float* __restrict__ hf, const unsigned int* __restrict__ ep,
    int t0, int nsteps)
{
    extern __shared__ __align__(16) char smem[];
    unsigned short* Wsm = (unsigned short*)smem;                      // 48 x WPAD
    float (*red)[4][WROWS][RPAD] =
        (float (*)[4][WROWS][RPAD])(smem + WROWS * WPAD * 2);

    const int tid = threadIdx.x;
    const int wg  = blockIdx.x;
    const int grp = wg & 3, sidx = wg >> 2;
    const int b0 = grp * 16, j0 = sidx * 16;

    const unsigned int ebase = ep[0] * 1024u;   // uniform (bumped before launch)

    // ---- stage w_hh slice -> LDS bf16 (rows: [gate*16+u][k]) ----
    #pragma unroll 4
    for (int it = 0; it < 48; ++it) {
        const int i   = it * 256 + tid;
        const int row = i >> 8;                     // 0..47 (256 float4 per row)
        const int c4  = (i & 255) * 4;
        const int gate = row >> 4, uu = row & 15;
        const float4 v = *(const float4*)(w_hh + (size_t)(gate * RNN + j0 + uu) * RNN + c4);
        unsigned short* dst = &Wsm[row * WPAD + c4];
        dst[0] = f2bf(v.x); dst[1] = f2bf(v.y); dst[2] = f2bf(v.z); dst[3] = f2bf(v.w);
    }

    // ---- gate-thread identity: (unit u 0..15, batch bl 0..15) ----
    const int u  = tid & 15;
    const int bl = tid >> 4;
    const int j  = j0 + u;
    const int b  = b0 + bl;
    const float bhr = b_hh[j], bhi = b_hh[RNN + j], bhn = b_hh[2 * RNN + j];

    float h_reg;
    if (t0 == 0) {
        h_reg = 0.f;
        // h(0) = 0, tag ebase+0, in buf0. Fire-and-forget; consumers poll it.
        __hip_atomic_store(&hb0[(size_t)b * RNN + j], ebase << 16,
                           __ATOMIC_RELAXED, __HIP_MEMORY_SCOPE_AGENT);
    } else {
        h_reg = hf[(size_t)b * RNN + j];    // f32 state from previous launch
    }
    __syncthreads();                        // Wsm staged

    // gi(t=0) rolling prefetch regs
    {
        // loaded below into gir/gii/gin
    }
    size_t gb0 = (size_t)b * G3 + j;
    float gir = bf2f(gi[gb0]);
    float gii = bf2f(gi[gb0 + RNN]);
    float gin = bf2f(gi[gb0 + 2 * RNN]);

    // ---- MFMA identity: wave kq = K quarter; lr = batch col / unit row ----
    const int lane = tid & 63, kq = tid >> 6;
    const int lr = lane & 15, lq = lane >> 4;
    const unsigned short* wbase = Wsm + kq * 256 + lq * 8;
    const unsigned int* hpo0 = hb0 + (size_t)(b0 + lr) * RNN + kq * 256 + lq * 8;
    const unsigned int* hpo1 = hb1 + (size_t)(b0 + lr) * RNN + kq * 256 + lq * 8;
    unsigned int* hw0 = hb0 + (size_t)b * RNN + j;
    unsigned int* hw1 = hb1 + (size_t)b * RNN + j;

    for (int t = 0; t < nsteps; ++t) {
        const int g = t0 + t;                               // global step index
        const unsigned int texp = (ebase + (unsigned)g) << 16;
        const unsigned int* hp = (g & 1) ? hpo1 : hpo0;     // h(g) lives in buf[g&1]
        unsigned int* hwp      = (g & 1) ? hw0  : hw1;      // h(g+1) -> buf[(g+1)&1]

        // issue gi(t+1) prefetch early; values consumed at step end
        const int tn = (t + 1 < nsteps) ? t + 1 : t;
        const size_t gbn = ((size_t)tn * BATCH + b) * G3 + j;
        const float ngr = bf2f(gi[gbn]);
        const float ngi = bf2f(gi[gbn + RNN]);
        const float ngn = bf2f(gi[gbn + 2 * RNN]);

        // ---- prefilter spin: 8 sampled dwords (32 B/lane/iter) ----
        for (;;) {
            unsigned int s = 0;
            #pragma unroll
            for (int ks = 0; ks < 8; ++ks)
                s |= __hip_atomic_load(hp + ks * 32, __ATOMIC_RELAXED,
                                       __HIP_MEMORY_SCOPE_AGENT) ^ texp;
            if (__all((s & 0xFFFF0000u) == 0)) break;
        }

        // ---- full tagged load (16 x dwordx4 sc0 sc1) + full verify ----
        u32x4 q0[8], q1[8];
        for (;;) {
            #pragma unroll
            for (int ks = 0; ks < 8; ++ks) {
                asm volatile("global_load_dwordx4 %0, %1, off sc0 sc1"
                             : "=v"(q0[ks]) : "v"(hp + ks * 32) : "memory");
                asm volatile("global_load_dwordx4 %0, %1, off sc0 sc1"
                             : "=v"(q1[ks]) : "v"(hp + ks * 32 + 4) : "memory");
            }
            asm volatile("s_waitcnt vmcnt(0)" ::: "memory");
            __builtin_amdgcn_sched_barrier(0);   // rule 18: fence VALU past waitcnt
            unsigned int s = 0;
            #pragma unroll
            for (int ks = 0; ks < 8; ++ks) {
                s |= (q0[ks].x ^ texp) | (q0[ks].y ^ texp)
                   | (q0[ks].z ^ texp) | (q0[ks].w ^ texp);
                s |= (q1[ks].x ^ texp) | (q1[ks].y ^ texp)
                   | (q1[ks].z ^ texp) | (q1[ks].w ^ texp);
            }
            if (__all((s & 0xFFFF0000u) == 0)) break;   // every dword is step g
        }

        // pack low bf16 halves -> 8 MFMA B-fragments (v_perm: 1 op per pair)
        short8 hfrag[8];
        #pragma unroll
        for (int ks = 0; ks < 8; ++ks) {
            union { unsigned int d[4]; short8 s8; } pk;
            pk.d[0] = __builtin_amdgcn_perm(q0[ks].y, q0[ks].x, 0x05040100u);
            pk.d[1] = __builtin_amdgcn_perm(q0[ks].w, q0[ks].z, 0x05040100u);
            pk.d[2] = __builtin_amdgcn_perm(q1[ks].y, q1[ks].x, 0x05040100u);
            pk.d[3] = __builtin_amdgcn_perm(q1[ks].w, q1[ks].z, 0x05040100u);
            hfrag[ks] = pk.s8;
        }

        f32x4 acc[3];
        acc[0] = (f32x4){0.f, 0.f, 0.f, 0.f};
        acc[1] = (f32x4){0.f, 0.f, 0.f, 0.f};
        acc[2] = (f32x4){0.f, 0.f, 0.f, 0.f};
        #pragma unroll
        for (int ks = 0; ks < 8; ++ks) {
            const int k = ks * 32;
            #pragma unroll
            for (int gt = 0; gt < 3; ++gt) {
                const short8 a = *(const short8*)(wbase + (gt * 16 + lr) * WPAD + k);
                acc[gt] = __builtin_amdgcn_mfma_f32_16x16x32_bf16(a, hfrag[ks],
                                                                  acc[gt], 0, 0, 0);
            }
        }
        float (*rcur)[WROWS][RPAD] = red[t & 1];
        #pragma unroll
        for (int gt = 0; gt < 3; ++gt)
            #pragma unroll
            for (int q = 0; q < 4; ++q)
                rcur[kq][gt * 16 + lq * 4 + q][lr] = acc[gt][q];  // C: row=lq*4+q
        __syncthreads();

        const float ghr = rcur[0][u][bl]      + rcur[1][u][bl]
                        + rcur[2][u][bl]      + rcur[3][u][bl];
        const float ghi = rcur[0][16 + u][bl] + rcur[1][16 + u][bl]
                        + rcur[2][16 + u][bl] + rcur[3][16 + u][bl];
        const float ghn = rcur[0][32 + u][bl] + rcur[1][32 + u][bl]
                        + rcur[2][32 + u][bl] + rcur[3][32 + u][bl];
        const float rr = sigmoidf_(gir + ghr + bhr);
        const float zz = sigmoidf_(gii + ghi + bhi);
        const float nn = tanhf_(gin + rr * (ghn + bhn));
        h_reg = zz * nn + (1.f - zz) * h_reg;

        // tagged h(g+1): fire-and-forget, tag is in-band -> no drain, no flag
        __hip_atomic_store(hwp, (texp + 0x10000u) | (unsigned)f2bf(h_reg),
                           __ATOMIC_RELAXED, __HIP_MEMORY_SCOPE_AGENT);
        gir = ngr; gii = ngi; gin = ngn;
        // no trailing barrier: next step writes red[(t+1)&1]; cross-WG WAR on
        // the h buffers is excluded by the tag-gated step-monotone dep DAG.
    }
    hf[(size_t)b * RNN + j] = h_reg;
}

// ============================================================================
// K3: out[b,o] = h_last[b,:] . fc_w[o,:] + fc_b[o]
// ============================================================================
__global__ __launch_bounds__(256) void out_kernel(
    const float* __restrict__ hf, const float* __restrict__ fc_w,
    const float* __restrict__ fc_b, float* __restrict__ out)
{
    __shared__ float red[256];
    const int bidx = blockIdx.x, tid = threadIdx.x;
    const int o = tid & 3, seg = tid >> 2;
    const float* hp = hf   + (size_t)bidx * RNN + seg * 16;
    const float* wp = fc_w + (size_t)o * RNN + seg * 16;
    float acc = 0.f;
    #pragma unroll
    for (int i = 0; i < 16; ++i) acc += hp[i] * wp[i];
    red[tid] = acc;
    __syncthreads();
    if (tid < 4) {
        float sv = fc_b[tid];
        #pragma unroll 8
        for (int q = 0; q < 64; ++q) sv += red[q * 4 + tid];
        out[bidx * 4 + tid] = sv;
    }
}

extern "C" void kernel_launch(void* const* d_in, const int* in_sizes, int n_in,
                              void* d_out, int out_size, void* d_ws, size_t ws_size,
                              hipStream_t stream)
{
    const int*   x     = (const int*)d_in[0];
    const float* emb   = (const float*)d_in[1];
    const float* w_ih  = (const float*)d_in[2];
    const float* w_hh  = (const float*)d_in[3];
    const float* b_ih  = (const float*)d_in[4];
    const float* b_hh  = (const float*)d_in[5];
    const float* fc_w  = (const float*)d_in[6];
    const float* fc_b  = (const float*)d_in[7];
    float*       out   = (float*)d_out;

    // Fused path needs gi for all 512 steps (201.3 MB); fall back to 4 chunks
    // if the workspace is too small (deterministic per deployment).
    // aux: hb0/hb1 (u32 tagged), hf (f32), epoch dword.
    const size_t aux = 3 * (size_t)BATCH * RNN * 4 + 256;
    const int tch  = (ws_size >= (size_t)T_TOTAL * BATCH * G3 * 2 + aux) ? 512 : 128;
    const int nchk = T_TOTAL / tch;

    char* ws = (char*)d_ws;
    unsigned short* gi_buf = (unsigned short*)ws;
    size_t off = (size_t)tch * BATCH * G3 * 2;
    unsigned int* hb0 = (unsigned int*)(ws + off); off += (size_t)BATCH * RNN * 4;
    unsigned int* hb1 = (unsigned int*)(ws + off); off += (size_t)BATCH * RNN * 4;
    float*        hf  = (float*)(ws + off);        off += (size_t)BATCH * RNN * 4;
    unsigned int* ep  = (unsigned int*)(ws + off); // persistent epoch (garbage OK)

    hipFuncSetAttribute((const void*)rec_kernel,
                        hipFuncAttributeMaxDynamicSharedMemorySize, SMEM_BYTES);

    epoch_kernel<<<dim3(1), dim3(1), 0, stream>>>(ep);

    for (int c = 0; c < nchk; ++c) {
        int t0 = c * tch, ns = tch;
        gi_kernel<<<dim3(tch * BATCH / 128, 24), dim3(256), 0, stream>>>(
            x, emb, w_ih, b_ih, gi_buf, t0);
        void* args[9];
        args[0] = (void*)&gi_buf; args[1] = (void*)&w_hh; args[2] = (void*)&b_hh;
        args[3] = (void*)&hb0;    args[4] = (void*)&hb1;  args[5] = (void*)&hf;
        args[6] = (void*)&ep;     args[7] = (void*)&t0;   args[8] = (void*)&ns;
        hipLaunchCooperativeKernel((const void*)rec_kernel, dim3(NWG), dim3(256),
                                   args, SMEM_BYTES, stream);
    }
    out_kernel<<<dim3(BATCH), dim3(256), 0, stream>>>(hf, fc_w, fc_b, out);
}

// Round 2
// 2285.923 us; speedup vs baseline: 1.3125x; 1.3125x over previous
//
#include <hip/hip_runtime.h>
#include <hip/hip_bf16.h>

typedef __attribute__((ext_vector_type(8))) short  short8;   // 8 bf16 (4 VGPRs) MFMA frag
typedef __attribute__((ext_vector_type(4))) float  f32x4;    // MFMA accum frag

#define T_TOTAL 512
#define BATCH   64
#define VOCAB   32000
#define EMB     512
#define RNN     1024
#define G3      3072      // 3*RNN
#define WROWS   48        // 3 gates x 16 units per WG
#define WPAD    1032      // LDS row stride (shorts): 16B-aligned, 2-way bank alias (free)
#define RPAD    18        // red[] batch stride (floats): max 2-way (free)
#define NWG     256
#define NGRP    4         // independent batch groups (16 batches each)
#define NLINE   4         // arrival lines per group: one per unit-quarter (16 WGs each)
#define SMEM_BYTES (WROWS * WPAD * 2 + 4 * WROWS * RPAD * 4)   // 99072 + 13824 = 112896

// ---- bf16 helpers ----
__device__ __forceinline__ unsigned short f2bf(float f) {
    union { float f; unsigned int u; } v; v.f = f;
    unsigned int r = v.u + 0x7fffu + ((v.u >> 16) & 1u);   // round-nearest-even
    return (unsigned short)(r >> 16);
}
__device__ __forceinline__ float bf2f(unsigned short h) {
    union { unsigned int u; float f; } v; v.u = ((unsigned int)h) << 16;
    return v.f;
}
__device__ __forceinline__ float sigmoidf_(float x) { return 1.f / (1.f + __expf(-x)); }
__device__ __forceinline__ float tanhf_(float x) {
    float ax = fabsf(x);
    float e2 = __expf(-2.f * ax);
    float t  = (1.f - e2) / (1.f + e2);
    return x < 0.f ? -t : t;
}

__global__ void bar_init(unsigned int* bar) {
    for (int i = threadIdx.x; i < NGRP * 256; i += 256) bar[i] = 0;
}

// f32 -> bf16 pre-convert (8 elems/thread). One-shot per launch; BW-bound.
__global__ __launch_bounds__(256) void cvt_bf16_kernel(
    const float* __restrict__ s, unsigned short* __restrict__ d, int n8)
{
    const int i = blockIdx.x * 256 + threadIdx.x;
    if (i >= n8) return;
    const float4 a = ((const float4*)s)[i * 2];
    const float4 b = ((const float4*)s)[i * 2 + 1];
    short8 v;
    v[0] = f2bf(a.x); v[1] = f2bf(a.y); v[2] = f2bf(a.z); v[3] = f2bf(a.w);
    v[4] = f2bf(b.x); v[5] = f2bf(b.y); v[6] = f2bf(b.z); v[7] = f2bf(b.w);
    ((short8*)d)[i] = v;
}

// ============================================================================
// K1: gi = emb_table[x] @ w_ih^T + b_ih, 128x128 tile (m93 pattern).
// BF=true: A/B pre-converted bf16 (half the staging bytes, zero convert VALU).
// BF=false: proven f32-staging fallback (workspace too small for bf16 copies).
// ============================================================================
template<bool BF>
__global__ __launch_bounds__(256) void gi_kernel(
    const int* __restrict__ x, const void* __restrict__ embp,
    const void* __restrict__ wihp, const float* __restrict__ b_ih,
    unsigned short* __restrict__ gi, int t0)
{
    __shared__ __align__(16) unsigned short Asm[128 * 40];
    __shared__ __align__(16) unsigned short Bsm[128 * 40];

    const int tid = threadIdx.x;
    const int m0 = blockIdx.x * 128;        // local row (t_local*64 + b)
    const int n0 = blockIdx.y * 128;

    const int r    = tid >> 1;              // 0..127
    const int half = tid & 1;               // 16-elem half of the 32-col chunk
    const int xi = x[t0 * BATCH + m0 + r];  // gather index (global row)
    unsigned short* adst = &Asm[r * 40 + half * 16];
    unsigned short* bdst = &Bsm[r * 40 + half * 16];

    const int lane = tid & 63, wv = tid >> 6;
    const int m_off = (wv & 1) * 64, n_off = (wv >> 1) * 64;
    const int lr = lane & 15, lq = lane >> 4;

    f32x4 acc[4][4];
    #pragma unroll
    for (int i = 0; i < 4; ++i)
        #pragma unroll
        for (int j = 0; j < 4; ++j) acc[i][j] = (f32x4){0.f, 0.f, 0.f, 0.f};

    if constexpr (BF) {
        const unsigned short* arow = (const unsigned short*)embp
                                   + (size_t)xi * EMB + half * 16;
        const unsigned short* brow = (const unsigned short*)wihp
                                   + (size_t)(n0 + r) * EMB + half * 16;
        for (int k0 = 0; k0 < EMB; k0 += 32) {
            const short8 av0 = *(const short8*)(arow + k0);
            const short8 av1 = *(const short8*)(arow + k0 + 8);
            const short8 bv0 = *(const short8*)(brow + k0);
            const short8 bv1 = *(const short8*)(brow + k0 + 8);
            __syncthreads();  // previous iter's frag reads done
            *(short8*)(adst)     = av0;
            *(short8*)(adst + 8) = av1;
            *(short8*)(bdst)     = bv0;
            *(short8*)(bdst + 8) = bv1;
            __syncthreads();

            short8 fa[4], fb[4];
            #pragma unroll
            for (int i = 0; i < 4; ++i) {
                fa[i] = *(const short8*)&Asm[(m_off + i * 16 + lr) * 40 + lq * 8];
                fb[i] = *(const short8*)&Bsm[(n_off + i * 16 + lr) * 40 + lq * 8];
            }
            #pragma unroll
            for (int mi = 0; mi < 4; ++mi)
                #pragma unroll
                for (int ni = 0; ni < 4; ++ni)
                    acc[mi][ni] = __builtin_amdgcn_mfma_f32_16x16x32_bf16(
                        fa[mi], fb[ni], acc[mi][ni], 0, 0, 0);
        }
    } else {
        const float* arow = (const float*)embp + (size_t)xi * EMB + half * 16;
        const float* brow = (const float*)wihp + (size_t)(n0 + r) * EMB + half * 16;
        for (int k0 = 0; k0 < EMB; k0 += 32) {
            const float4 a0 = *(const float4*)(arow + k0);
            const float4 a1 = *(const float4*)(arow + k0 + 4);
            const float4 a2 = *(const float4*)(arow + k0 + 8);
            const float4 a3 = *(const float4*)(arow + k0 + 12);
            const float4 b0 = *(const float4*)(brow + k0);
            const float4 b1 = *(const float4*)(brow + k0 + 4);
            const float4 b2 = *(const float4*)(brow + k0 + 8);
            const float4 b3 = *(const float4*)(brow + k0 + 12);
            __syncthreads();
            short8 av0, av1, bv0, bv1;
            av0[0]=f2bf(a0.x); av0[1]=f2bf(a0.y); av0[2]=f2bf(a0.z); av0[3]=f2bf(a0.w);
            av0[4]=f2bf(a1.x); av0[5]=f2bf(a1.y); av0[6]=f2bf(a1.z); av0[7]=f2bf(a1.w);
            av1[0]=f2bf(a2.x); av1[1]=f2bf(a2.y); av1[2]=f2bf(a2.z); av1[3]=f2bf(a2.w);
            av1[4]=f2bf(a3.x); av1[5]=f2bf(a3.y); av1[6]=f2bf(a3.z); av1[7]=f2bf(a3.w);
            bv0[0]=f2bf(b0.x); bv0[1]=f2bf(b0.y); bv0[2]=f2bf(b0.z); bv0[3]=f2bf(b0.w);
            bv0[4]=f2bf(b1.x); bv0[5]=f2bf(b1.y); bv0[6]=f2bf(b1.z); bv0[7]=f2bf(b1.w);
            bv1[0]=f2bf(b2.x); bv1[1]=f2bf(b2.y); bv1[2]=f2bf(b2.z); bv1[3]=f2bf(b2.w);
            bv1[4]=f2bf(b3.x); bv1[5]=f2bf(b3.y); bv1[6]=f2bf(b3.z); bv1[7]=f2bf(b3.w);
            *(short8*)(adst)     = av0;
            *(short8*)(adst + 8) = av1;
            *(short8*)(bdst)     = bv0;
            *(short8*)(bdst + 8) = bv1;
            __syncthreads();

            short8 fa[4], fb[4];
            #pragma unroll
            for (int i = 0; i < 4; ++i) {
                fa[i] = *(const short8*)&Asm[(m_off + i * 16 + lr) * 40 + lq * 8];
                fb[i] = *(const short8*)&Bsm[(n_off + i * 16 + lr) * 40 + lq * 8];
            }
            #pragma unroll
            for (int mi = 0; mi < 4; ++mi)
                #pragma unroll
                for (int ni = 0; ni < 4; ++ni)
                    acc[mi][ni] = __builtin_amdgcn_mfma_f32_16x16x32_bf16(
                        fa[mi], fb[ni], acc[mi][ni], 0, 0, 0);
        }
    }

    float bia[4];
    #pragma unroll
    for (int ni = 0; ni < 4; ++ni) bia[ni] = b_ih[n0 + n_off + ni * 16 + lr];
    #pragma unroll
    for (int mi = 0; mi < 4; ++mi)
        #pragma unroll
        for (int ni = 0; ni < 4; ++ni) {
            const int n = n0 + n_off + ni * 16 + lr;
            #pragma unroll
            for (int q = 0; q < 4; ++q) {
                const int m = m0 + m_off + mi * 16 + lq * 4 + q;  // C: row=lq*4+q
                gi[(size_t)m * G3 + n] = f2bf(acc[mi][ni][q] + bia[ni]);
            }
        }
}

// ============================================================================
// K2: recurrence. R7 structure (1756 us measured) + quarter-split arrival:
// one line per (grp, unit-quarter), 16 arrivals each (vs 32), and each wave
// waits ONLY on its kq quarter's line via a lane-0 spin + wave reconvergence
// (replaces the block-wide release __syncthreads; 2 block barriers/step).
// WAR safety unchanged: the h store still sits behind the red-phase
// __syncthreads joining all 4 waves, so a store at step t happens-after all
// 64 grp-WGs arrived for t-1 (i.e. after every reader of the target buffer
// finished); the drain __syncthreads separates gate-reads from red-writes.
// ============================================================================
__global__ __launch_bounds__(256, 1) void rec_kernel(
    const unsigned short* __restrict__ gi,
    const float* __restrict__ w_hh, const float* __restrict__ b_hh,
    unsigned short* __restrict__ hb0, unsigned short* __restrict__ hb1,
    float* __restrict__ hf, unsigned int* bar, int t0, int nsteps, int pbase)
{
    extern __shared__ __align__(16) char smem[];
    unsigned short* Wsm = (unsigned short*)smem;                      // 48 x WPAD
    float (*red)[WROWS][RPAD] = (float (*)[WROWS][RPAD])(smem + WROWS * WPAD * 2);

    const int tid = threadIdx.x;
    const int wg  = blockIdx.x;
    const int grp = wg & 3, sidx = wg >> 2;
    const int b0 = grp * 16, j0 = sidx * 16;
    unsigned int* lines = &bar[grp * 256];          // 4 lines, 256B apart
    const int qw = sidx >> 4;                       // producer quarter (0..3)

    // ---- stage w_hh slice -> LDS bf16 (rows: [gate*16+u][k]) ----
    #pragma unroll 4
    for (int it = 0; it < 48; ++it) {
        const int i   = it * 256 + tid;
        const int row = i >> 8;                     // 0..47 (256 float4 per row)
        const int c4  = (i & 255) * 4;
        const int gate = row >> 4, uu = row & 15;
        const float4 v = *(const float4*)(w_hh + (size_t)(gate * RNN + j0 + uu) * RNN + c4);
        unsigned short* dst = &Wsm[row * WPAD + c4];
        dst[0] = f2bf(v.x); dst[1] = f2bf(v.y); dst[2] = f2bf(v.z); dst[3] = f2bf(v.w);
    }

    // ---- gate-thread identity: (unit u 0..15, batch bl 0..15) ----
    const int u  = tid & 15;
    const int bl = tid >> 4;
    const int j  = j0 + u;
    const int b  = b0 + bl;
    const float bhr = b_hh[j], bhi = b_hh[RNN + j], bhn = b_hh[2 * RNN + j];

    float h_reg;
    if (t0 == 0) {
        h_reg = 0.f;
        if ((u & 1) == 0)
            __hip_atomic_store((unsigned int*)&hb0[b * RNN + j], 0u,
                               __ATOMIC_RELAXED, __HIP_MEMORY_SCOPE_AGENT);
    } else {
        h_reg = hf[b * RNN + j];            // f32 state from previous launch
    }
    __syncthreads();                        // Wsm staged + h-init stores drained
    if (tid == 0)
        __hip_atomic_fetch_add(&lines[qw * 64], 1u,
                               __ATOMIC_RELAXED, __HIP_MEMORY_SCOPE_AGENT);

    // gi(t=0) prefetch during initial spin (gi is locally indexed)
    size_t gb = (size_t)b * G3 + j0 + u;
    float gir = bf2f(gi[gb]);
    float gii = bf2f(gi[gb + RNN]);
    float gin = bf2f(gi[gb + 2 * RNN]);

    // ---- MFMA identity: wave kq = K quarter; lr = batch col / unit row ----
    const int lane = tid & 63, kq = tid >> 6;
    const int lr = lane & 15, lq = lane >> 4;
    const unsigned short* wbase = Wsm + kq * 256 + lq * 8;
    const size_t hoff = ((size_t)(b0 + lr) * RNN + kq * 256 + lq * 8) >> 2;  // in u64s
    unsigned int* myline = &lines[kq * 64];          // consumer quarter line

    // per-wave wait: lane 0 spins until this quarter's 16 producers arrived
    if (lane == 0) {
        while (__hip_atomic_load(myline, __ATOMIC_RELAXED,
                                 __HIP_MEMORY_SCOPE_AGENT)
               < (unsigned)(pbase + 1) * 16u)
            __builtin_amdgcn_s_sleep(1);
    }
    asm volatile("" ::: "memory");           // compiler fence: no hoist past spin

    for (int t = 0; t < nsteps; ++t) {
        const unsigned short* hrd = (t & 1) ? hb1 : hb0;
        unsigned short*       hwr = (t & 1) ? hb0 : hb1;

        // preload this wave's 16 h u64s (pipelined sc1 MALL reads)
        union { unsigned long long q[2]; short8 s8; } hv[8];
        const unsigned long long* hp = (const unsigned long long*)hrd + hoff;
        #pragma unroll
        for (int ks = 0; ks < 8; ++ks) {
            hv[ks].q[0] = __hip_atomic_load(hp + ks * 8,     __ATOMIC_RELAXED,
                                            __HIP_MEMORY_SCOPE_AGENT);
            hv[ks].q[1] = __hip_atomic_load(hp + ks * 8 + 1, __ATOMIC_RELAXED,
                                            __HIP_MEMORY_SCOPE_AGENT);
        }

        f32x4 acc[3];
        acc[0] = (f32x4){0.f, 0.f, 0.f, 0.f};
        acc[1] = (f32x4){0.f, 0.f, 0.f, 0.f};
        acc[2] = (f32x4){0.f, 0.f, 0.f, 0.f};
        #pragma unroll
        for (int ks = 0; ks < 8; ++ks) {
            const int k = ks * 32;
            #pragma unroll
            for (int gt = 0; gt < 3; ++gt) {
                const short8 a = *(const short8*)(wbase + (gt * 16 + lr) * WPAD + k);
                acc[gt] = __builtin_amdgcn_mfma_f32_16x16x32_bf16(a, hv[ks].s8,
                                                                  acc[gt], 0, 0, 0);
            }
        }
        #pragma unroll
        for (int gt = 0; gt < 3; ++gt)
            #pragma unroll
            for (int q = 0; q < 4; ++q)
                red[kq][gt * 16 + lq * 4 + q][lr] = acc[gt][q];   // C: row=lq*4+q
        __syncthreads();

        const float ghr = red[0][u][bl]      + red[1][u][bl]
                        + red[2][u][bl]      + red[3][u][bl];
        const float ghi = red[0][16 + u][bl] + red[1][16 + u][bl]
                        + red[2][16 + u][bl] + red[3][16 + u][bl];
        const float ghn = red[0][32 + u][bl] + red[1][32 + u][bl]
                        + red[2][32 + u][bl] + red[3][32 + u][bl];
        const float rr = sigmoidf_(gir + ghr + bhr);
        const float zz = sigmoidf_(gii + ghi + bhi);
        const float nn = tanhf_(gin + rr * (ghn + bhn));
        h_reg = zz * nn + (1.f - zz) * h_reg;

        // packed pair store (u, u^1 share one dword), write-through sc1
        unsigned int hvv = (unsigned int)f2bf(h_reg);
        unsigned int ovv = __shfl_xor((int)hvv, 1);
        if ((u & 1) == 0)
            __hip_atomic_store((unsigned int*)&hwr[b * RNN + j],
                               hvv | (ovv << 16), __ATOMIC_RELAXED,
                               __HIP_MEMORY_SCOPE_AGENT);

        __syncthreads();                     // all waves' h stores drained
        if (tid == 0)
            __hip_atomic_fetch_add(&lines[qw * 64], 1u,
                                   __ATOMIC_RELAXED, __HIP_MEMORY_SCOPE_AGENT);

        // prefetch gi(t+1) while the spin is in flight
        const int tn = (t + 1 < nsteps) ? t + 1 : t;
        gb = ((size_t)tn * BATCH + b) * G3 + j0 + u;
        const float ngr = bf2f(gi[gb]);
        const float ngi = bf2f(gi[gb + RNN]);
        const float ngn = bf2f(gi[gb + 2 * RNN]);

        if (lane == 0) {
            while (__hip_atomic_load(myline, __ATOMIC_RELAXED,
                                     __HIP_MEMORY_SCOPE_AGENT)
                   < (unsigned)(pbase + 2 + t) * 16u)
                __builtin_amdgcn_s_sleep(1);
        }
        asm volatile("" ::: "memory");
        gir = ngr; gii = ngi; gin = ngn;
    }
    hf[b * RNN + j] = h_reg;
}

// ============================================================================
// K3: out[b,o] = h_last[b,:] . fc_w[o,:] + fc_b[o]
// ============================================================================
__global__ __launch_bounds__(256) void out_kernel(
    const float* __restrict__ hf, const float* __restrict__ fc_w,
    const float* __restrict__ fc_b, float* __restrict__ out)
{
    __shared__ float red[256];
    const int bidx = blockIdx.x, tid = threadIdx.x;
    const int o = tid & 3, seg = tid >> 2;
    const float* hp = hf   + (size_t)bidx * RNN + seg * 16;
    const float* wp = fc_w + (size_t)o * RNN + seg * 16;
    float acc = 0.f;
    #pragma unroll
    for (int i = 0; i < 16; ++i) acc += hp[i] * wp[i];
    red[tid] = acc;
    __syncthreads();
    if (tid < 4) {
        float sv = fc_b[tid];
        #pragma unroll 8
        for (int q = 0; q < 64; ++q) sv += red[q * 4 + tid];
        out[bidx * 4 + tid] = sv;
    }
}

extern "C" void kernel_launch(void* const* d_in, const int* in_sizes, int n_in,
                              void* d_out, int out_size, void* d_ws, size_t ws_size,
                              hipStream_t stream)
{
    const int*   x     = (const int*)d_in[0];
    const float* emb   = (const float*)d_in[1];
    const float* w_ih  = (const float*)d_in[2];
    const float* w_hh  = (const float*)d_in[3];
    const float* b_ih  = (const float*)d_in[4];
    const float* b_hh  = (const float*)d_in[5];
    const float* fc_w  = (const float*)d_in[6];
    const float* fc_b  = (const float*)d_in[7];
    float*       out   = (float*)d_out;

    // Workspace: gi (201.3 MB fused) + h buffers + bar [+ bf16 copies of
    // emb/w_ih if room]. Fallbacks are deterministic per deployment.
    const size_t aux = 2 * (size_t)BATCH * RNN * 2 + (size_t)BATCH * RNN * 4
                     + NGRP * 256 * 4;
    const size_t gi_full  = (size_t)T_TOTAL * BATCH * G3 * 2;
    const size_t embbf_b  = (size_t)VOCAB * EMB * 2;
    const size_t wihbf_b  = (size_t)G3 * EMB * 2;
    const bool fused  = ws_size >= gi_full + aux;
    const bool bfpath = ws_size >= gi_full + aux + embbf_b + wihbf_b;
    const int tch  = fused ? 512 : 128;
    const int nchk = T_TOTAL / tch;

    char* ws = (char*)d_ws;
    unsigned short* gi_buf = (unsigned short*)ws;
    size_t off = (size_t)tch * BATCH * G3 * 2;
    unsigned short* hb0 = (unsigned short*)(ws + off); off += (size_t)BATCH * RNN * 2;
    unsigned short* hb1 = (unsigned short*)(ws + off); off += (size_t)BATCH * RNN * 2;
    float*          hf  = (float*)(ws + off);          off += (size_t)BATCH * RNN * 4;
    unsigned int*   bar = (unsigned int*)(ws + off);   off += NGRP * 256 * 4;
    unsigned short* embbf = (unsigned short*)(ws + off); off += embbf_b;
    unsigned short* wihbf = (unsigned short*)(ws + off);

    hipFuncSetAttribute((const void*)rec_kernel,
                        hipFuncAttributeMaxDynamicSharedMemorySize, SMEM_BYTES);

    bar_init<<<dim3(1), dim3(256), 0, stream>>>(bar);
    if (bfpath) {
        cvt_bf16_kernel<<<dim3((VOCAB * EMB / 8 + 255) / 256), dim3(256), 0, stream>>>(
            emb, embbf, VOCAB * EMB / 8);
        cvt_bf16_kernel<<<dim3((G3 * EMB / 8 + 255) / 256), dim3(256), 0, stream>>>(
            w_ih, wihbf, G3 * EMB / 8);
    }

    for (int c = 0; c < nchk; ++c) {
        int t0 = c * tch, ns = tch, pb = c * (tch + 1);
        if (bfpath)
            gi_kernel<true><<<dim3(tch * BATCH / 128, 24), dim3(256), 0, stream>>>(
                x, (const void*)embbf, (const void*)wihbf, b_ih, gi_buf, t0);
        else
            gi_kernel<false><<<dim3(tch * BATCH / 128, 24), dim3(256), 0, stream>>>(
                x, (const void*)emb, (const void*)w_ih, b_ih, gi_buf, t0);
        void* args[10];
        args[0] = (void*)&gi_buf; args[1] = (void*)&w_hh; args[2] = (void*)&b_hh;
        args[3] = (void*)&hb0;    args[4] = (void*)&hb1;  args[5] = (void*)&hf;
        args[6] = (void*)&bar;    args[7] = (void*)&t0;   args[8] = (void*)&ns;
        args[9] = (void*)&pb;
        hipLaunchCooperativeKernel((const void*)rec_kernel, dim3(NWG), dim3(256),
                                   args, SMEM_BYTES, stream);
    }
    out_kernel<<<dim3(BATCH), dim3(256), 0, stream>>>(hf, fc_w, fc_b, out);
}

// Round 4
// 2242.955 us; speedup vs baseline: 1.3376x; 1.0192x over previous
//
#include <hip/hip_runtime.h>
#include <hip/hip_bf16.h>

typedef __attribute__((ext_vector_type(8))) short  short8;   // 8 bf16 (4 VGPRs) MFMA frag
typedef __attribute__((ext_vector_type(4))) float  f32x4;    // MFMA accum frag

#define T_TOTAL 512
#define BATCH   64
#define VOCAB   32000
#define EMB     512
#define RNN     1024
#define G3      3072      // 3*RNN
#define WROWS   48        // 3 gates x 16 units per WG
#define WPAD    1032      // LDS row stride (shorts): 16B-aligned, 2-way bank alias (free)
#define RPAD    18        // red[] batch stride (floats): max 2-way (free)
#define NWG     256
#define NGRP    4         // independent batch groups (16 batches each)
#define SMEM_BYTES (WROWS * WPAD * 2 + 4 * WROWS * RPAD * 4)   // 99072 + 13824 = 112896

// ---- bf16 helpers ----
__device__ __forceinline__ unsigned short f2bf(float f) {
    union { float f; unsigned int u; } v; v.f = f;
    unsigned int r = v.u + 0x7fffu + ((v.u >> 16) & 1u);   // round-nearest-even
    return (unsigned short)(r >> 16);
}
__device__ __forceinline__ float bf2f(unsigned short h) {
    union { unsigned int u; float f; } v; v.u = ((unsigned int)h) << 16;
    return v.f;
}
__device__ __forceinline__ float sigmoidf_(float x) { return 1.f / (1.f + __expf(-x)); }
__device__ __forceinline__ float tanhf_(float x) {
    float ax = fabsf(x);
    float e2 = __expf(-2.f * ax);
    float t  = (1.f - e2) / (1.f + e2);
    return x < 0.f ? -t : t;
}

// ============================================================================
// Barrier: per-WG flag stores (NO same-address RMW chain).
// Group g owns 64 flag dwords (256 B, 4 cache lines). Arrive: after the
// drain __syncthreads (vmcnt 0 -> h stores at MALL), thread0 plain-stores
// its phase to its own dword. Wait: wave 0's 64 lanes load the 64 flags
// (one coalesced 256B transaction = one RTT) and __all(v >= ph); release
// via __syncthreads. Same AGENT store/load primitive pair as the h payload
// itself (proven); flags monotone within a launch (bar zeroed per replay).
// ============================================================================
__device__ __forceinline__ void gbar_arrive(unsigned int* flags, int sidx,
                                            unsigned int ph) {
    __syncthreads();                         // all waves' h stores drained (vmcnt 0)
    if (threadIdx.x == 0)
        __hip_atomic_store(&flags[sidx], ph,
                           __ATOMIC_RELAXED, __HIP_MEMORY_SCOPE_AGENT);
}
__device__ __forceinline__ void gbar_wait(unsigned int* flags, unsigned int ph) {
    if (threadIdx.x < 64) {                  // wave 0, all 64 lanes
        for (;;) {
            unsigned int v = __hip_atomic_load(&flags[threadIdx.x],
                                               __ATOMIC_RELAXED,
                                               __HIP_MEMORY_SCOPE_AGENT);
            if (__all(v >= ph)) break;
            __builtin_amdgcn_s_sleep(1);
        }
    }
    __syncthreads();
}

__global__ void bar_init(unsigned int* bar) {
    for (int i = threadIdx.x; i < NGRP * 256; i += 256) bar[i] = 0;
}

// f32 -> bf16 pre-convert (8 elems/thread). One-shot per launch; BW-bound.
__global__ __launch_bounds__(256) void cvt_bf16_kernel(
    const float* __restrict__ s, unsigned short* __restrict__ d, int n8)
{
    const int i = blockIdx.x * 256 + threadIdx.x;
    if (i >= n8) return;
    const float4 a = ((const float4*)s)[i * 2];
    const float4 b = ((const float4*)s)[i * 2 + 1];
    short8 v;
    v[0] = f2bf(a.x); v[1] = f2bf(a.y); v[2] = f2bf(a.z); v[3] = f2bf(a.w);
    v[4] = f2bf(b.x); v[5] = f2bf(b.y); v[6] = f2bf(b.z); v[7] = f2bf(b.w);
    ((short8*)d)[i] = v;
}

// ============================================================================
// K1: gi = emb_table[x] @ w_ih^T + b_ih, 128x128 tile (m93 pattern).
// BF=true: A/B pre-converted bf16 (half the staging bytes, zero convert VALU).
// BF=false: proven f32-staging fallback.
// ============================================================================
template<bool BF>
__global__ __launch_bounds__(256) void gi_kernel(
    const int* __restrict__ x, const void* __restrict__ embp,
    const void* __restrict__ wihp, const float* __restrict__ b_ih,
    unsigned short* __restrict__ gi, int t0)
{
    __shared__ __align__(16) unsigned short Asm[128 * 40];
    __shared__ __align__(16) unsigned short Bsm[128 * 40];

    const int tid = threadIdx.x;
    const int m0 = blockIdx.x * 128;        // local row (t_local*64 + b)
    const int n0 = blockIdx.y * 128;

    const int r    = tid >> 1;              // 0..127
    const int half = tid & 1;               // 16-elem half of the 32-col chunk
    const int xi = x[t0 * BATCH + m0 + r];  // gather index (global row)
    unsigned short* adst = &Asm[r * 40 + half * 16];
    unsigned short* bdst = &Bsm[r * 40 + half * 16];

    const int lane = tid & 63, wv = tid >> 6;
    const int m_off = (wv & 1) * 64, n_off = (wv >> 1) * 64;
    const int lr = lane & 15, lq = lane >> 4;

    f32x4 acc[4][4];
    #pragma unroll
    for (int i = 0; i < 4; ++i)
        #pragma unroll
        for (int j = 0; j < 4; ++j) acc[i][j] = (f32x4){0.f, 0.f, 0.f, 0.f};

    if constexpr (BF) {
        const unsigned short* arow = (const unsigned short*)embp
                                   + (size_t)xi * EMB + half * 16;
        const unsigned short* brow = (const unsigned short*)wihp
                                   + (size_t)(n0 + r) * EMB + half * 16;
        for (int k0 = 0; k0 < EMB; k0 += 32) {
            const short8 av0 = *(const short8*)(arow + k0);
            const short8 av1 = *(const short8*)(arow + k0 + 8);
            const short8 bv0 = *(const short8*)(brow + k0);
            const short8 bv1 = *(const short8*)(brow + k0 + 8);
            __syncthreads();  // previous iter's frag reads done
            *(short8*)(adst)     = av0;
            *(short8*)(adst + 8) = av1;
            *(short8*)(bdst)     = bv0;
            *(short8*)(bdst + 8) = bv1;
            __syncthreads();

            short8 fa[4], fb[4];
            #pragma unroll
            for (int i = 0; i < 4; ++i) {
                fa[i] = *(const short8*)&Asm[(m_off + i * 16 + lr) * 40 + lq * 8];
                fb[i] = *(const short8*)&Bsm[(n_off + i * 16 + lr) * 40 + lq * 8];
            }
            #pragma unroll
            for (int mi = 0; mi < 4; ++mi)
                #pragma unroll
                for (int ni = 0; ni < 4; ++ni)
                    acc[mi][ni] = __builtin_amdgcn_mfma_f32_16x16x32_bf16(
                        fa[mi], fb[ni], acc[mi][ni], 0, 0, 0);
        }
    } else {
        const float* arow = (const float*)embp + (size_t)xi * EMB + half * 16;
        const float* brow = (const float*)wihp + (size_t)(n0 + r) * EMB + half * 16;
        for (int k0 = 0; k0 < EMB; k0 += 32) {
            const float4 a0 = *(const float4*)(arow + k0);
            const float4 a1 = *(const float4*)(arow + k0 + 4);
            const float4 a2 = *(const float4*)(arow + k0 + 8);
            const float4 a3 = *(const float4*)(arow + k0 + 12);
            const float4 b0 = *(const float4*)(brow + k0);
            const float4 b1 = *(const float4*)(brow + k0 + 4);
            const float4 b2 = *(const float4*)(brow + k0 + 8);
            const float4 b3 = *(const float4*)(brow + k0 + 12);
            __syncthreads();
            short8 av0, av1, bv0, bv1;
            av0[0]=f2bf(a0.x); av0[1]=f2bf(a0.y); av0[2]=f2bf(a0.z); av0[3]=f2bf(a0.w);
            av0[4]=f2bf(a1.x); av0[5]=f2bf(a1.y); av0[6]=f2bf(a1.z); av0[7]=f2bf(a1.w);
            av1[0]=f2bf(a2.x); av1[1]=f2bf(a2.y); av1[2]=f2bf(a2.z); av1[3]=f2bf(a2.w);
            av1[4]=f2bf(a3.x); av1[5]=f2bf(a3.y); av1[6]=f2bf(a3.z); av1[7]=f2bf(a3.w);
            bv0[0]=f2bf(b0.x); bv0[1]=f2bf(b0.y); bv0[2]=f2bf(b0.z); bv0[3]=f2bf(b0.w);
            bv0[4]=f2bf(b1.x); bv0[5]=f2bf(b1.y); bv0[6]=f2bf(b1.z); bv0[7]=f2bf(b1.w);
            bv1[0]=f2bf(b2.x); bv1[1]=f2bf(b2.y); bv1[2]=f2bf(b2.z); bv1[3]=f2bf(b2.w);
            bv1[4]=f2bf(b3.x); bv1[5]=f2bf(b3.y); bv1[6]=f2bf(b3.z); bv1[7]=f2bf(b3.w);
            *(short8*)(adst)     = av0;
            *(short8*)(adst + 8) = av1;
            *(short8*)(bdst)     = bv0;
            *(short8*)(bdst + 8) = bv1;
            __syncthreads();

            short8 fa[4], fb[4];
            #pragma unroll
            for (int i = 0; i < 4; ++i) {
                fa[i] = *(const short8*)&Asm[(m_off + i * 16 + lr) * 40 + lq * 8];
                fb[i] = *(const short8*)&Bsm[(n_off + i * 16 + lr) * 40 + lq * 8];
            }
            #pragma unroll
            for (int mi = 0; mi < 4; ++mi)
                #pragma unroll
                for (int ni = 0; ni < 4; ++ni)
                    acc[mi][ni] = __builtin_amdgcn_mfma_f32_16x16x32_bf16(
                        fa[mi], fb[ni], acc[mi][ni], 0, 0, 0);
        }
    }

    float bia[4];
    #pragma unroll
    for (int ni = 0; ni < 4; ++ni) bia[ni] = b_ih[n0 + n_off + ni * 16 + lr];
    #pragma unroll
    for (int mi = 0; mi < 4; ++mi)
        #pragma unroll
        for (int ni = 0; ni < 4; ++ni) {
            const int n = n0 + n_off + ni * 16 + lr;
            #pragma unroll
            for (int q = 0; q < 4; ++q) {
                const int m = m0 + m_off + mi * 16 + lq * 4 + q;  // C: row=lq*4+q
                gi[(size_t)m * G3 + n] = f2bf(acc[mi][ni][q] + bia[ni]);
            }
        }
}

// ============================================================================
// K2: recurrence (R7 structure, measured best) with flag-store barrier.
// WG (grp, sidx): batches b0=grp*16..+16, units j0=sidx*16..+16; w_hh slice
// 48 rows in 99 KB dynamic LDS. Waves = K quarters, 3 gate-tile MFMAs per
// k-step. h ping-pong bf16 sc1; h_reg f32 in-register. Split-phase barrier
// with gi prefetch under the poll. 512 steps fused (or 128/chunk fallback).
// ============================================================================
__global__ __launch_bounds__(256, 1) void rec_kernel(
    const unsigned short* __restrict__ gi,
    const float* __restrict__ w_hh, const float* __restrict__ b_hh,
    unsigned short* __restrict__ hb0, unsigned short* __restrict__ hb1,
    float* __restrict__ hf, unsigned int* bar, int t0, int nsteps, int pbase)
{
    extern __shared__ __align__(16) char smem[];
    unsigned short* Wsm = (unsigned short*)smem;                      // 48 x WPAD
    float (*red)[WROWS][RPAD] = (float (*)[WROWS][RPAD])(smem + WROWS * WPAD * 2);

    const int tid = threadIdx.x;
    const int wg  = blockIdx.x;
    const int grp = wg & 3, sidx = wg >> 2;
    const int b0 = grp * 16, j0 = sidx * 16;
    unsigned int* flags = &bar[grp * 64];           // 64 per-WG flags (256 B)

    // ---- stage w_hh slice -> LDS bf16 (rows: [gate*16+u][k]) ----
    #pragma unroll 4
    for (int it = 0; it < 48; ++it) {
        const int i   = it * 256 + tid;
        const int row = i >> 8;                     // 0..47 (256 float4 per row)
        const int c4  = (i & 255) * 4;
        const int gate = row >> 4, uu = row & 15;
        const float4 v = *(const float4*)(w_hh + (size_t)(gate * RNN + j0 + uu) * RNN + c4);
        unsigned short* dst = &Wsm[row * WPAD + c4];
        dst[0] = f2bf(v.x); dst[1] = f2bf(v.y); dst[2] = f2bf(v.z); dst[3] = f2bf(v.w);
    }

    // ---- gate-thread identity: (unit u 0..15, batch bl 0..15) ----
    const int u  = tid & 15;
    const int bl = tid >> 4;
    const int j  = j0 + u;
    const int b  = b0 + bl;
    const float bhr = b_hh[j], bhi = b_hh[RNN + j], bhn = b_hh[2 * RNN + j];

    float h_reg;
    if (t0 == 0) {
        h_reg = 0.f;
        if ((u & 1) == 0)
            __hip_atomic_store((unsigned int*)&hb0[b * RNN + j], 0u,
                               __ATOMIC_RELAXED, __HIP_MEMORY_SCOPE_AGENT);
    } else {
        h_reg = hf[b * RNN + j];            // f32 state from previous launch
    }
    gbar_arrive(flags, sidx, (unsigned)(pbase + 1));

    // gi(t=0) prefetch during initial barrier poll (gi is locally indexed)
    size_t gb = (size_t)b * G3 + j0 + u;
    float gir = bf2f(gi[gb]);
    float gii = bf2f(gi[gb + RNN]);
    float gin = bf2f(gi[gb + 2 * RNN]);
    gbar_wait(flags, (unsigned)(pbase + 1));

    // ---- MFMA identity: wave kq = K quarter; lr = batch col / unit row ----
    const int lane = tid & 63, kq = tid >> 6;
    const int lr = lane & 15, lq = lane >> 4;
    const unsigned short* wbase = Wsm + kq * 256 + lq * 8;
    const size_t hoff = ((size_t)(b0 + lr) * RNN + kq * 256 + lq * 8) >> 2;  // in u64s

    for (int t = 0; t < nsteps; ++t) {
        const unsigned short* hrd = (t & 1) ? hb1 : hb0;
        unsigned short*       hwr = (t & 1) ? hb0 : hb1;

        // preload this wave's 16 h u64s (pipelined sc1 MALL reads)
        union { unsigned long long q[2]; short8 s8; } hv[8];
        const unsigned long long* hp = (const unsigned long long*)hrd + hoff;
        #pragma unroll
        for (int ks = 0; ks < 8; ++ks) {
            hv[ks].q[0] = __hip_atomic_load(hp + ks * 8,     __ATOMIC_RELAXED,
                                            __HIP_MEMORY_SCOPE_AGENT);
            hv[ks].q[1] = __hip_atomic_load(hp + ks * 8 + 1, __ATOMIC_RELAXED,
                                            __HIP_MEMORY_SCOPE_AGENT);
        }

        f32x4 acc[3];
        acc[0] = (f32x4){0.f, 0.f, 0.f, 0.f};
        acc[1] = (f32x4){0.f, 0.f, 0.f, 0.f};
        acc[2] = (f32x4){0.f, 0.f, 0.f, 0.f};
        #pragma unroll
        for (int ks = 0; ks < 8; ++ks) {
            const int k = ks * 32;
            #pragma unroll
            for (int gt = 0; gt < 3; ++gt) {
                const short8 a = *(const short8*)(wbase + (gt * 16 + lr) * WPAD + k);
                acc[gt] = __builtin_amdgcn_mfma_f32_16x16x32_bf16(a, hv[ks].s8,
                                                                  acc[gt], 0, 0, 0);
            }
        }
        #pragma unroll
        for (int gt = 0; gt < 3; ++gt)
            #pragma unroll
            for (int q = 0; q < 4; ++q)
                red[kq][gt * 16 + lq * 4 + q][lr] = acc[gt][q];   // C: row=lq*4+q
        __syncthreads();

        const float ghr = red[0][u][bl]      + red[1][u][bl]
                        + red[2][u][bl]      + red[3][u][bl];
        const float ghi = red[0][16 + u][bl] + red[1][16 + u][bl]
                        + red[2][16 + u][bl] + red[3][16 + u][bl];
        const float ghn = red[0][32 + u][bl] + red[1][32 + u][bl]
                        + red[2][32 + u][bl] + red[3][32 + u][bl];
        const float rr = sigmoidf_(gir + ghr + bhr);
        const float zz = sigmoidf_(gii + ghi + bhi);
        const float nn = tanhf_(gin + rr * (ghn + bhn));
        h_reg = zz * nn + (1.f - zz) * h_reg;

        // packed pair store (u, u^1 share one dword), write-through sc1
        unsigned int hvv = (unsigned int)f2bf(h_reg);
        unsigned int ovv = __shfl_xor((int)hvv, 1);
        if ((u & 1) == 0)
            __hip_atomic_store((unsigned int*)&hwr[b * RNN + j],
                               hvv | (ovv << 16), __ATOMIC_RELAXED,
                               __HIP_MEMORY_SCOPE_AGENT);

        gbar_arrive(flags, sidx, (unsigned)(pbase + 2 + t));
        // prefetch gi(t+1) while the barrier poll is in flight
        const int tn = (t + 1 < nsteps) ? t + 1 : t;
        gb = ((size_t)tn * BATCH + b) * G3 + j0 + u;
        const float ngr = bf2f(gi[gb]);
        const float ngi = bf2f(gi[gb + RNN]);
        const float ngn = bf2f(gi[gb + 2 * RNN]);
        gbar_wait(flags, (unsigned)(pbase + 2 + t));
        gir = ngr; gii = ngi; gin = ngn;
    }
    hf[b * RNN + j] = h_reg;
}

// ============================================================================
// K3: out[b,o] = h_last[b,:] . fc_w[o,:] + fc_b[o]
// ============================================================================
__global__ __launch_bounds__(256) void out_kernel(
    const float* __restrict__ hf, const float* __restrict__ fc_w,
    const float* __restrict__ fc_b, float* __restrict__ out)
{
    __shared__ float red[256];
    const int bidx = blockIdx.x, tid = threadIdx.x;
    const int o = tid & 3, seg = tid >> 2;
    const float* hp = hf   + (size_t)bidx * RNN + seg * 16;
    const float* wp = fc_w + (size_t)o * RNN + seg * 16;
    float acc = 0.f;
    #pragma unroll
    for (int i = 0; i < 16; ++i) acc += hp[i] * wp[i];
    red[tid] = acc;
    __syncthreads();
    if (tid < 4) {
        float sv = fc_b[tid];
        #pragma unroll 8
        for (int q = 0; q < 64; ++q) sv += red[q * 4 + tid];
        out[bidx * 4 + tid] = sv;
    }
}

extern "C" void kernel_launch(void* const* d_in, const int* in_sizes, int n_in,
                              void* d_out, int out_size, void* d_ws, size_t ws_size,
                              hipStream_t stream)
{
    const int*   x     = (const int*)d_in[0];
    const float* emb   = (const float*)d_in[1];
    const float* w_ih  = (const float*)d_in[2];
    const float* w_hh  = (const float*)d_in[3];
    const float* b_ih  = (const float*)d_in[4];
    const float* b_hh  = (const float*)d_in[5];
    const float* fc_w  = (const float*)d_in[6];
    const float* fc_b  = (const float*)d_in[7];
    float*       out   = (float*)d_out;

    // Workspace: gi (201.3 MB fused) + h buffers + bar [+ bf16 copies of
    // emb/w_ih if room]. Fallbacks are deterministic per deployment.
    const size_t bar_b   = (size_t)NGRP * 256 * 4;
    const size_t aux     = 2 * (size_t)BATCH * RNN * 2
                         + (size_t)BATCH * RNN * 4 + bar_b;
    const size_t gi_full = (size_t)T_TOTAL * BATCH * G3 * 2;
    const size_t embbf_b = (size_t)VOCAB * EMB * 2;
    const size_t wihbf_b = (size_t)G3 * EMB * 2;
    const bool fused  = ws_size >= gi_full + aux;
    const bool bfpath = ws_size >= gi_full + aux + embbf_b + wihbf_b;
    const int tch  = fused ? 512 : 128;
    const int nchk = T_TOTAL / tch;

    char* ws = (char*)d_ws;
    unsigned short* gi_buf = (unsigned short*)ws;
    size_t off = (size_t)tch * BATCH * G3 * 2;
    unsigned short* hb0 = (unsigned short*)(ws + off); off += (size_t)BATCH * RNN * 2;
    unsigned short* hb1 = (unsigned short*)(ws + off); off += (size_t)BATCH * RNN * 2;
    float*          hf  = (float*)(ws + off);          off += (size_t)BATCH * RNN * 4;
    unsigned int*   bar = (unsigned int*)(ws + off);   off += bar_b;
    unsigned short* embbf = (unsigned short*)(ws + off); off += embbf_b;
    unsigned short* wihbf = (unsigned short*)(ws + off);

    hipFuncSetAttribute((const void*)rec_kernel,
                        hipFuncAttributeMaxDynamicSharedMemorySize, SMEM_BYTES);

    bar_init<<<dim3(1), dim3(256), 0, stream>>>(bar);
    if (bfpath) {
        cvt_bf16_kernel<<<dim3((VOCAB * EMB / 8 + 255) / 256), dim3(256), 0, stream>>>(
            emb, embbf, VOCAB * EMB / 8);
        cvt_bf16_kernel<<<dim3((G3 * EMB / 8 + 255) / 256), dim3(256), 0, stream>>>(
            w_ih, wihbf, G3 * EMB / 8);
    }

    for (int c = 0; c < nchk; ++c) {
        int t0 = c * tch, ns = tch, pb = c * (tch + 1);
        if (bfpath)
            gi_kernel<true><<<dim3(tch * BATCH / 128, 24), dim3(256), 0, stream>>>(
                x, (const void*)embbf, (const void*)wihbf, b_ih, gi_buf, t0);
        else
            gi_kernel<false><<<dim3(tch * BATCH / 128, 24), dim3(256), 0, stream>>>(
                x, (const void*)emb, (const void*)w_ih, b_ih, gi_buf, t0);
        void* args[10];
        args[0] = (void*)&gi_buf; args[1] = (void*)&w_hh; args[2] = (void*)&b_hh;
        args[3] = (void*)&hb0;    args[4] = (void*)&hb1;  args[5] = (void*)&hf;
        args[6] = (void*)&bar;    args[7] = (void*)&t0;   args[8] = (void*)&ns;
        args[9] = (void*)&pb;
        hipLaunchCooperativeKernel((const void*)rec_kernel, dim3(NWG), dim3(256),
                                   args, SMEM_BYTES, stream);
    }
    out_kernel<<<dim3(BATCH), dim3(256), 0, stream>>>(hf, fc_w, fc_b, out);
}

// Round 6
// 2098.693 us; speedup vs baseline: 1.4296x; 1.0687x over previous
//
#include <hip/hip_runtime.h>
#include <hip/hip_bf16.h>

typedef __attribute__((ext_vector_type(8))) short  short8;   // 8 bf16 (4 VGPRs) MFMA frag
typedef __attribute__((ext_vector_type(4))) float  f32x4;    // MFMA accum frag

#define T_TOTAL 512
#define BATCH   64
#define VOCAB   32000
#define EMB     512
#define RNN     1024
#define G3      3072      // 3*RNN
#define WROWS   48        // 3 gates x 16 units per WG
#define WPAD    1032      // LDS row stride (shorts): 16B-aligned, 2-way bank alias (free)
#define RPAD    18        // red[] batch stride (floats): max 2-way (free)
#define NWG     256
#define NGRP    4         // independent batch groups (16 batches each)
#define NLINE   2         // arrival lines per group (32 WGs each)
#define SMEM_BYTES (WROWS * WPAD * 2 + 4 * WROWS * RPAD * 4)   // 99072 + 13824 = 112896

// gi kernel LDS: A resident 128 x 520 shorts (+520 stride = 2-way free) + B 128 x 40
#define APAD    520
#define GI_SMEM (128 * APAD * 2 + 128 * 40 * 2)               // 133120 + 10240 = 143360

// ---- bf16 helpers ----
__device__ __forceinline__ unsigned short f2bf(float f) {
    union { float f; unsigned int u; } v; v.f = f;
    unsigned int r = v.u + 0x7fffu + ((v.u >> 16) & 1u);   // round-nearest-even
    return (unsigned short)(r >> 16);
}
__device__ __forceinline__ float bf2f(unsigned short h) {
    union { unsigned int u; float f; } v; v.u = ((unsigned int)h) << 16;
    return v.f;
}
__device__ __forceinline__ float sigmoidf_(float x) { return 1.f / (1.f + __expf(-x)); }
__device__ __forceinline__ float tanhf_(float x) {
    float ax = fabsf(x);
    float e2 = __expf(-2.f * ax);
    float t  = (1.f - e2) / (1.f + e2);
    return x < 0.f ? -t : t;
}

// ============================================================================
// R7 barrier (best measured): split-phase per-group, flag-hop-free.
// Arrive: thread0 RMWs its 32-WG arrival line. Wait: lanes 0/1 poll BOTH
// arrival lines directly (exec-masked spin until each hits 32*ph).
// ============================================================================
__device__ __forceinline__ void gbar_arrive(unsigned int* lines, int lid,
                                            unsigned int ph) {
    __syncthreads();                         // all waves' h stores drained (vmcnt 0)
    if (threadIdx.x == 0)
        __hip_atomic_fetch_add(&lines[lid * 64], 1u,
                               __ATOMIC_RELAXED, __HIP_MEMORY_SCOPE_AGENT);
}
__device__ __forceinline__ void gbar_wait(unsigned int* lines, unsigned int ph) {
    if (threadIdx.x < NLINE) {               // lanes 0,1 of wave 0, exec-masked spin
        while (__hip_atomic_load(&lines[threadIdx.x * 64], __ATOMIC_RELAXED,
                                 __HIP_MEMORY_SCOPE_AGENT) < ph * 32u)
            __builtin_amdgcn_s_sleep(1);
    }
    __syncthreads();
}

__global__ void bar_init(unsigned int* bar) {
    for (int i = threadIdx.x; i < NGRP * 256; i += 256) bar[i] = 0;
}

// f32 -> bf16 pre-convert (8 elems/thread). One-shot per launch; BW-bound.
__global__ __launch_bounds__(256) void cvt_bf16_kernel(
    const float* __restrict__ s, unsigned short* __restrict__ d, int n8)
{
    const int i = blockIdx.x * 256 + threadIdx.x;
    if (i >= n8) return;
    const float4 a = ((const float4*)s)[i * 2];
    const float4 b = ((const float4*)s)[i * 2 + 1];
    short8 v;
    v[0] = f2bf(a.x); v[1] = f2bf(a.y); v[2] = f2bf(a.z); v[3] = f2bf(a.w);
    v[4] = f2bf(b.x); v[5] = f2bf(b.y); v[6] = f2bf(b.z); v[7] = f2bf(b.w);
    ((short8*)d)[i] = v;
}

// ============================================================================
// K1: gi = emb_table[x] @ w_ih^T + b_ih.
// NEW STRUCTURE: one WG per 128-row m-tile; A (gathered emb rows, 128x512)
// staged ONCE into resident LDS; loop 24/gridDim.y n-tiles internally with
// the proven per-32-chunk B staging + 4x4 MFMA inner loop. Cuts A re-reads
// 24x (790 MB -> 33 MB); B (w_ih) stays L2-resident. BF=bf16 inputs.
// ============================================================================
template<bool BF>
__global__ __launch_bounds__(256) void gi_kernel(
    const int* __restrict__ x, const void* __restrict__ embp,
    const void* __restrict__ wihp, const float* __restrict__ b_ih,
    unsigned short* __restrict__ gi, int t0)
{
    extern __shared__ __align__(16) unsigned short gsm[];
    unsigned short* Asm = gsm;                    // 128 x APAD (resident)
    unsigned short* Bsm = gsm + 128 * APAD;       // 128 x 40   (per k-chunk)

    const int tid = threadIdx.x;
    const int m0 = blockIdx.x * 128;              // local row (t_local*64 + b)
    const int nseg   = 24 / gridDim.y;            // n-tiles per WG
    const int nstart = blockIdx.y * nseg;

    const int r    = tid >> 1;                    // 0..127
    const int half = tid & 1;                     // 16-elem half of each 32-chunk
    const int xi = x[t0 * BATCH + m0 + r];        // gather index (global row)

    // ---- stage A once: row r, all 512 cols ----
    if constexpr (BF) {
        const unsigned short* arow = (const unsigned short*)embp
                                   + (size_t)xi * EMB + half * 16;
        #pragma unroll 4
        for (int k0 = 0; k0 < EMB; k0 += 32) {
            const short8 a0 = *(const short8*)(arow + k0);
            const short8 a1 = *(const short8*)(arow + k0 + 8);
            *(short8*)&Asm[r * APAD + k0 + half * 16]     = a0;
            *(short8*)&Asm[r * APAD + k0 + half * 16 + 8] = a1;
        }
    } else {
        const float* arow = (const float*)embp + (size_t)xi * EMB + half * 16;
        #pragma unroll 4
        for (int k0 = 0; k0 < EMB; k0 += 32) {
            const float4 a0 = *(const float4*)(arow + k0);
            const float4 a1 = *(const float4*)(arow + k0 + 4);
            const float4 a2 = *(const float4*)(arow + k0 + 8);
            const float4 a3 = *(const float4*)(arow + k0 + 12);
            short8 v0, v1;
            v0[0]=f2bf(a0.x); v0[1]=f2bf(a0.y); v0[2]=f2bf(a0.z); v0[3]=f2bf(a0.w);
            v0[4]=f2bf(a1.x); v0[5]=f2bf(a1.y); v0[6]=f2bf(a1.z); v0[7]=f2bf(a1.w);
            v1[0]=f2bf(a2.x); v1[1]=f2bf(a2.y); v1[2]=f2bf(a2.z); v1[3]=f2bf(a2.w);
            v1[4]=f2bf(a3.x); v1[5]=f2bf(a3.y); v1[6]=f2bf(a3.z); v1[7]=f2bf(a3.w);
            *(short8*)&Asm[r * APAD + k0 + half * 16]     = v0;
            *(short8*)&Asm[r * APAD + k0 + half * 16 + 8] = v1;
        }
    }

    const int lane = tid & 63, wv = tid >> 6;
    const int m_off = (wv & 1) * 64, n_off = (wv >> 1) * 64;
    const int lr = lane & 15, lq = lane >> 4;

    for (int nt = 0; nt < nseg; ++nt) {
        const int n0 = (nstart + nt) * 128;

        f32x4 acc[4][4];
        #pragma unroll
        for (int i = 0; i < 4; ++i)
            #pragma unroll
            for (int j = 0; j < 4; ++j) acc[i][j] = (f32x4){0.f, 0.f, 0.f, 0.f};

        for (int k0 = 0; k0 < EMB; k0 += 32) {
            // load B chunk (w_ih rows n0..n0+128, cols k0..k0+32) to regs
            short8 bv0, bv1;
            if constexpr (BF) {
                const unsigned short* brow = (const unsigned short*)wihp
                                           + (size_t)(n0 + r) * EMB + half * 16;
                bv0 = *(const short8*)(brow + k0);
                bv1 = *(const short8*)(brow + k0 + 8);
            } else {
                const float* brow = (const float*)wihp
                                  + (size_t)(n0 + r) * EMB + half * 16;
                const float4 b0 = *(const float4*)(brow + k0);
                const float4 b1 = *(const float4*)(brow + k0 + 4);
                const float4 b2 = *(const float4*)(brow + k0 + 8);
                const float4 b3 = *(const float4*)(brow + k0 + 12);
                bv0[0]=f2bf(b0.x); bv0[1]=f2bf(b0.y); bv0[2]=f2bf(b0.z); bv0[3]=f2bf(b0.w);
                bv0[4]=f2bf(b1.x); bv0[5]=f2bf(b1.y); bv0[6]=f2bf(b1.z); bv0[7]=f2bf(b1.w);
                bv1[0]=f2bf(b2.x); bv1[1]=f2bf(b2.y); bv1[2]=f2bf(b2.z); bv1[3]=f2bf(b2.w);
                bv1[4]=f2bf(b3.x); bv1[5]=f2bf(b3.y); bv1[6]=f2bf(b3.z); bv1[7]=f2bf(b3.w);
            }
            __syncthreads();                 // previous chunk's frag reads done
            *(short8*)&Bsm[r * 40 + half * 16]     = bv0;
            *(short8*)&Bsm[r * 40 + half * 16 + 8] = bv1;
            __syncthreads();

            short8 fa[4], fb[4];
            #pragma unroll
            for (int i = 0; i < 4; ++i) {
                fa[i] = *(const short8*)&Asm[(m_off + i * 16 + lr) * APAD + k0 + lq * 8];
                fb[i] = *(const short8*)&Bsm[(n_off + i * 16 + lr) * 40 + lq * 8];
            }
            #pragma unroll
            for (int mi = 0; mi < 4; ++mi)
                #pragma unroll
                for (int ni = 0; ni < 4; ++ni)
                    acc[mi][ni] = __builtin_amdgcn_mfma_f32_16x16x32_bf16(
                        fa[mi], fb[ni], acc[mi][ni], 0, 0, 0);
        }

        float bia[4];
        #pragma unroll
        for (int ni = 0; ni < 4; ++ni) bia[ni] = b_ih[n0 + n_off + ni * 16 + lr];
        #pragma unroll
        for (int mi = 0; mi < 4; ++mi)
            #pragma unroll
            for (int ni = 0; ni < 4; ++ni) {
                const int n = n0 + n_off + ni * 16 + lr;
                #pragma unroll
                for (int q = 0; q < 4; ++q) {
                    const int m = m0 + m_off + mi * 16 + lq * 4 + q;  // C: row=lq*4+q
                    gi[(size_t)m * G3 + n] = f2bf(acc[mi][ni][q] + bia[ni]);
                }
            }
    }
}

// ============================================================================
// K2: recurrence (R7/R0 structure — best measured, VERBATIM). WG (grp, sidx):
// batches b0=grp*16..+16, units j0=sidx*16..+16; w_hh slice 48 rows in 99 KB
// dynamic LDS. Waves = K quarters, 3 gate-tile MFMAs per k-step. h ping-pong
// bf16 sc1; h_reg f32 in-register. Split-phase barrier with gi prefetch
// under the spin. 512 steps fused (or 128/chunk fallback).
// ============================================================================
__global__ __launch_bounds__(256, 1) void rec_kernel(
    const unsigned short* __restrict__ gi,
    const float* __restrict__ w_hh, const float* __restrict__ b_hh,
    unsigned short* __restrict__ hb0, unsigned short* __restrict__ hb1,
    float* __restrict__ hf, unsigned int* bar, int t0, int nsteps, int pbase)
{
    extern __shared__ __align__(16) char smem[];
    unsigned short* Wsm = (unsigned short*)smem;                      // 48 x WPAD
    float (*red)[WROWS][RPAD] = (float (*)[WROWS][RPAD])(smem + WROWS * WPAD * 2);

    const int tid = threadIdx.x;
    const int wg  = blockIdx.x;
    const int grp = wg & 3, sidx = wg >> 2;
    const int b0 = grp * 16, j0 = sidx * 16;
    unsigned int* lines = &bar[grp * 256];          // 2 lines, 256B apart
    const int lid = sidx & (NLINE - 1);

    // ---- stage w_hh slice -> LDS bf16 (rows: [gate*16+u][k]) ----
    #pragma unroll 4
    for (int it = 0; it < 48; ++it) {
        const int i   = it * 256 + tid;
        const int row = i >> 8;                     // 0..47 (256 float4 per row)
        const int c4  = (i & 255) * 4;
        const int gate = row >> 4, uu = row & 15;
        const float4 v = *(const float4*)(w_hh + (size_t)(gate * RNN + j0 + uu) * RNN + c4);
        unsigned short* dst = &Wsm[row * WPAD + c4];
        dst[0] = f2bf(v.x); dst[1] = f2bf(v.y); dst[2] = f2bf(v.z); dst[3] = f2bf(v.w);
    }

    // ---- gate-thread identity: (unit u 0..15, batch bl 0..15) ----
    const int u  = tid & 15;
    const int bl = tid >> 4;
    const int j  = j0 + u;
    const int b  = b0 + bl;
    const float bhr = b_hh[j], bhi = b_hh[RNN + j], bhn = b_hh[2 * RNN + j];

    float h_reg;
    if (t0 == 0) {
        h_reg = 0.f;
        if ((u & 1) == 0)
            __hip_atomic_store((unsigned int*)&hb0[b * RNN + j], 0u,
                               __ATOMIC_RELAXED, __HIP_MEMORY_SCOPE_AGENT);
    } else {
        h_reg = hf[b * RNN + j];            // f32 state from previous launch
    }
    gbar_arrive(lines, lid, (unsigned)(pbase + 1));

    // gi(t=0) prefetch during initial barrier spin (gi is locally indexed)
    size_t gb = (size_t)b * G3 + j0 + u;
    float gir = bf2f(gi[gb]);
    float gii = bf2f(gi[gb + RNN]);
    float gin = bf2f(gi[gb + 2 * RNN]);
    gbar_wait(lines, (unsigned)(pbase + 1));

    // ---- MFMA identity: wave kq = K quarter; lr = batch col / unit row ----
    const int lane = tid & 63, kq = tid >> 6;
    const int lr = lane & 15, lq = lane >> 4;
    const unsigned short* wbase = Wsm + kq * 256 + lq * 8;
    const size_t hoff = ((size_t)(b0 + lr) * RNN + kq * 256 + lq * 8) >> 2;  // in u64s

    for (int t = 0; t < nsteps; ++t) {
        const unsigned short* hrd = (t & 1) ? hb1 : hb0;
        unsigned short*       hwr = (t & 1) ? hb0 : hb1;

        // preload this wave's 16 h u64s (pipelined sc1 MALL reads)
        union { unsigned long long q[2]; short8 s8; } hv[8];
        const unsigned long long* hp = (const unsigned long long*)hrd + hoff;
        #pragma unroll
        for (int ks = 0; ks < 8; ++ks) {
            hv[ks].q[0] = __hip_atomic_load(hp + ks * 8,     __ATOMIC_RELAXED,
                                            __HIP_MEMORY_SCOPE_AGENT);
            hv[ks].q[1] = __hip_atomic_load(hp + ks * 8 + 1, __ATOMIC_RELAXED,
                                            __HIP_MEMORY_SCOPE_AGENT);
        }

        f32x4 acc[3];
        acc[0] = (f32x4){0.f, 0.f, 0.f, 0.f};
        acc[1] = (f32x4){0.f, 0.f, 0.f, 0.f};
        acc[2] = (f32x4){0.f, 0.f, 0.f, 0.f};
        #pragma unroll
        for (int ks = 0; ks < 8; ++ks) {
            const int k = ks * 32;
            #pragma unroll
            for (int gt = 0; gt < 3; ++gt) {
                const short8 a = *(const short8*)(wbase + (gt * 16 + lr) * WPAD + k);
                acc[gt] = __builtin_amdgcn_mfma_f32_16x16x32_bf16(a, hv[ks].s8,
                                                                  acc[gt], 0, 0, 0);
            }
        }
        #pragma unroll
        for (int gt = 0; gt < 3; ++gt)
            #pragma unroll
            for (int q = 0; q < 4; ++q)
                red[kq][gt * 16 + lq * 4 + q][lr] = acc[gt][q];   // C: row=lq*4+q, col=lr
        __syncthreads();

        const float ghr = red[0][u][bl]      + red[1][u][bl]
                        + red[2][u][bl]      + red[3][u][bl];
        const float ghi = red[0][16 + u][bl] + red[1][16 + u][bl]
                        + red[2][16 + u][bl] + red[3][16 + u][bl];
        const float ghn = red[0][32 + u][bl] + red[1][32 + u][bl]
                        + red[2][32 + u][bl] + red[3][32 + u][bl];
        const float rr = sigmoidf_(gir + ghr + bhr);
        const float zz = sigmoidf_(gii + ghi + bhi);
        const float nn = tanhf_(gin + rr * (ghn + bhn));
        h_reg = zz * nn + (1.f - zz) * h_reg;

        // packed pair store (u, u^1 share one dword), write-through sc1
        unsigned int hvv = (unsigned int)f2bf(h_reg);
        unsigned int ovv = __shfl_xor((int)hvv, 1);
        if ((u & 1) == 0)
            __hip_atomic_store((unsigned int*)&hwr[b * RNN + j],
                               hvv | (ovv << 16), __ATOMIC_RELAXED,
                               __HIP_MEMORY_SCOPE_AGENT);

        gbar_arrive(lines, lid, (unsigned)(pbase + 2 + t));
        // prefetch gi(t+1) while the barrier spin is in flight
        const int tn = (t + 1 < nsteps) ? t + 1 : t;
        gb = ((size_t)tn * BATCH + b) * G3 + j0 + u;
        const float ngr = bf2f(gi[gb]);
        const float ngi = bf2f(gi[gb + RNN]);
        const float ngn = bf2f(gi[gb + 2 * RNN]);
        gbar_wait(lines, (unsigned)(pbase + 2 + t));
        gir = ngr; gii = ngi; gin = ngn;
    }
    hf[b * RNN + j] = h_reg;
}

// ============================================================================
// K3: out[b,o] = h_last[b,:] . fc_w[o,:] + fc_b[o]
// ============================================================================
__global__ __launch_bounds__(256) void out_kernel(
    const float* __restrict__ hf, const float* __restrict__ fc_w,
    const float* __restrict__ fc_b, float* __restrict__ out)
{
    __shared__ float red[256];
    const int bidx = blockIdx.x, tid = threadIdx.x;
    const int o = tid & 3, seg = tid >> 2;
    const float* hp = hf   + (size_t)bidx * RNN + seg * 16;
    const float* wp = fc_w + (size_t)o * RNN + seg * 16;
    float acc = 0.f;
    #pragma unroll
    for (int i = 0; i < 16; ++i) acc += hp[i] * wp[i];
    red[tid] = acc;
    __syncthreads();
    if (tid < 4) {
        float sv = fc_b[tid];
        #pragma unroll 8
        for (int q = 0; q < 64; ++q) sv += red[q * 4 + tid];
        out[bidx * 4 + tid] = sv;
    }
}

extern "C" void kernel_launch(void* const* d_in, const int* in_sizes, int n_in,
                              void* d_out, int out_size, void* d_ws, size_t ws_size,
                              hipStream_t stream)
{
    const int*   x     = (const int*)d_in[0];
    const float* emb   = (const float*)d_in[1];
    const float* w_ih  = (const float*)d_in[2];
    const float* w_hh  = (const float*)d_in[3];
    const float* b_ih  = (const float*)d_in[4];
    const float* b_hh  = (const float*)d_in[5];
    const float* fc_w  = (const float*)d_in[6];
    const float* fc_b  = (const float*)d_in[7];
    float*       out   = (float*)d_out;

    // Workspace: gi (201.3 MB fused) + h buffers + bar [+ bf16 copies of
    // emb/w_ih if room]. Fallbacks are deterministic per deployment.
    const size_t bar_b   = (size_t)NGRP * 256 * 4;
    const size_t aux     = 2 * (size_t)BATCH * RNN * 2
                         + (size_t)BATCH * RNN * 4 + bar_b;
    const size_t gi_full = (size_t)T_TOTAL * BATCH * G3 * 2;
    const size_t embbf_b = (size_t)VOCAB * EMB * 2;
    const size_t wihbf_b = (size_t)G3 * EMB * 2;
    const bool fused  = ws_size >= gi_full + aux;
    const bool bfpath = ws_size >= gi_full + aux + embbf_b + wihbf_b;
    const int tch  = fused ? 512 : 128;
    const int nchk = T_TOTAL / tch;

    char* ws = (char*)d_ws;
    unsigned short* gi_buf = (unsigned short*)ws;
    size_t off = (size_t)tch * BATCH * G3 * 2;
    unsigned short* hb0 = (unsigned short*)(ws + off); off += (size_t)BATCH * RNN * 2;
    unsigned short* hb1 = (unsigned short*)(ws + off); off += (size_t)BATCH * RNN * 2;
    float*          hf  = (float*)(ws + off);          off += (size_t)BATCH * RNN * 4;
    unsigned int*   bar = (unsigned int*)(ws + off);   off += bar_b;
    unsigned short* embbf = (unsigned short*)(ws + off); off += embbf_b;
    unsigned short* wihbf = (unsigned short*)(ws + off);

    hipFuncSetAttribute((const void*)rec_kernel,
                        hipFuncAttributeMaxDynamicSharedMemorySize, SMEM_BYTES);
    hipFuncSetAttribute((const void*)gi_kernel<true>,
                        hipFuncAttributeMaxDynamicSharedMemorySize, GI_SMEM);
    hipFuncSetAttribute((const void*)gi_kernel<false>,
                        hipFuncAttributeMaxDynamicSharedMemorySize, GI_SMEM);

    bar_init<<<dim3(1), dim3(256), 0, stream>>>(bar);
    if (bfpath) {
        cvt_bf16_kernel<<<dim3((VOCAB * EMB / 8 + 255) / 256), dim3(256), 0, stream>>>(
            emb, embbf, VOCAB * EMB / 8);
        cvt_bf16_kernel<<<dim3((G3 * EMB / 8 + 255) / 256), dim3(256), 0, stream>>>(
            w_ih, wihbf, G3 * EMB / 8);
    }

    for (int c = 0; c < nchk; ++c) {
        int t0 = c * tch, ns = tch, pb = c * (tch + 1);
        // fused: 256 m-tiles x 1 (24 n-tiles each); chunked: 64 m-tiles x 4 (6 each)
        const dim3 gig = fused ? dim3(256, 1) : dim3(64, 4);
        if (bfpath)
            gi_kernel<true><<<gig, dim3(256), GI_SMEM, stream>>>(
                x, (const void*)embbf, (const void*)wihbf, b_ih, gi_buf, t0);
        else
            gi_kernel<false><<<gig, dim3(256), GI_SMEM, stream>>>(
                x, (const void*)emb, (const void*)w_ih, b_ih, gi_buf, t0);
        void* args[10];
        args[0] = (void*)&gi_buf; args[1] = (void*)&w_hh; args[2] = (void*)&b_hh;
        args[3] = (void*)&hb0;    args[4] = (void*)&hb1;  args[5] = (void*)&hf;
        args[6] = (void*)&bar;    args[7] = (void*)&t0;   args[8] = (void*)&ns;
        args[9] = (void*)&pb;
        hipLaunchCooperativeKernel((const void*)rec_kernel, dim3(NWG), dim3(256),
                                   args, SMEM_BYTES, stream);
    }
    out_kernel<<<dim3(BATCH), dim3(256), 0, stream>>>(hf, fc_w, fc_b, out);
}